// Round 2
// baseline (2912.768 us; speedup 1.0000x reference)
//
#include <hip/hip_runtime.h>
#include <cstdint>

// ---------------------------------------------------------------------------
// Seq2seq LSTM attention model, MI355X bf16-MFMA implementation.
//
//   prep:   cast/pack weights to bf16; Wcat_enc=[whh|wih] (K=1536),
//           Wdec=[whh|W2] (K=2048); pad x/z to K=128; zero h/c; combine biases
//   b2:     bias_dec = dec_bih + dec_bhh + dec_wih @ lin_b
//   W2:     GEMM dec_wih @ lin_w -> Wdec cols 1024..2047 (folds zero_mid)
//   feat:   GEMM [x;z]_pad @ wf_pad.T + bf -> feat[xz][t][b][d] bf16
//   enc:    10x { grouped (z=2) gates GEMM [h ; x_t] @ Wcat.T + bias; cell }
//   dec:    25x { attention -> atth; gates GEMM [atth ; h_n] @ Wdec.T; cell }
//   pose:   GEMM hs @ pose_w_pad.T + pose_b -> d_out (f32 [B,25,66])
//
// GEMM kernel: m97 structure — 128x128 tile, BK=64, 4 waves (2x2 of 64x64),
// global_load_lds width 16, ds_read_b128 fragments, mfma_f32_16x16x32_bf16.
//
// Arena aliasing: hs (52.4MB, decoder-phase) overlays
// [WcatE|dwih|linT|xpad|feat] (56.6MB, dead after encoder). Total ~166MB.
// ws_size guard: on insufficient scratch, fill d_out with (float)ws_size.
// ---------------------------------------------------------------------------

#define B_   1024
#define H_   1024
#define D_   512
#define G_   4096
#define TIN  10
#define TOUT 25

typedef __bf16 bf16x8 __attribute__((ext_vector_type(8)));
typedef float  f32x4  __attribute__((ext_vector_type(4)));

__device__ __forceinline__ unsigned short f2bf(float f) {
  unsigned int x = __builtin_bit_cast(unsigned int, f);
  x += 0x7fffu + ((x >> 16) & 1u);        // RNE
  return (unsigned short)(x >> 16);
}
__device__ __forceinline__ float bf2f(unsigned short u) {
  unsigned int x = ((unsigned int)u) << 16;
  return __builtin_bit_cast(float, x);
}

__device__ __forceinline__ void gload16(const void* g, void* l) {
  __builtin_amdgcn_global_load_lds(
      (const __attribute__((address_space(1))) void*)g,
      (__attribute__((address_space(3))) void*)l, 16, 0, 0);
}

// ---------------------------------------------------------------------------
// Generic bf16 GEMM: C[m,n] = sum_k A[m,k] * W[n,k] (+bias).
// A split at K1 between A1 (lda1) and A2 (lda2) for concat-K.
// MODE 0: f32 out + bias (gates). MODE 1: bf16 out remapped to feat layout.
// MODE 2: bf16 out strided (W2 into Wdec). MODE 3: pose output (n<66, f32).
// grid.z groups independent problems (the two encoders).
// ---------------------------------------------------------------------------
template <int MODE>
__launch_bounds__(256, 2)
__global__ void gemm_k(const unsigned short* __restrict__ A1,
                       const unsigned short* __restrict__ A2,
                       int lda1, int lda2, int K, int K1,
                       const unsigned short* __restrict__ W, int ldw,
                       const float* __restrict__ bias,
                       float* __restrict__ outF,
                       unsigned short* __restrict__ outB,
                       int ldout,
                       long a1_zs, long a2_zs, long w_zs, long bias_zs,
                       long out_zs) {
  __shared__ __align__(16) unsigned short As[128 * 64];
  __shared__ __align__(16) unsigned short Bs[128 * 64];
  const int tid  = threadIdx.x;
  const int lane = tid & 63;
  const int wave = tid >> 6;
  const int z    = blockIdx.z;
  const long m0  = (long)blockIdx.x * 128;
  const long n0  = (long)blockIdx.y * 128;
  const int wr   = (wave >> 1) * 64;
  const int wc   = (wave & 1) * 64;
  const int lrow = lane & 15;
  const int lk8  = (lane >> 4) * 8;

  f32x4 acc[4][4];
#pragma unroll
  for (int i = 0; i < 4; i++)
#pragma unroll
    for (int j = 0; j < 4; j++) acc[i][j] = f32x4{0.f, 0.f, 0.f, 0.f};

  const unsigned short* Wz  = W + (long)z * w_zs;
  const unsigned short* A1z = A1 + (long)z * a1_zs;
  const unsigned short* A2z = A2 ? (A2 + (long)z * a2_zs) : (const unsigned short*)0;

  for (int k0 = 0; k0 < K; k0 += 64) {
    const unsigned short* asrc;
    int ald, ak;
    if (k0 < K1) { asrc = A1z; ald = lda1; ak = k0; }
    else         { asrc = A2z; ald = lda2; ak = k0 - K1; }
#pragma unroll
    for (int i = 0; i < 4; i++) {
      int c  = i * 256 + tid;
      int r  = c >> 3;
      int c8 = (c & 7) * 8;
      gload16(asrc + (m0 + r) * (long)ald + ak + c8, &As[c * 8]);
      gload16(Wz + (n0 + r) * (long)ldw + k0 + c8, &Bs[c * 8]);
    }
    __syncthreads();
#pragma unroll
    for (int kk = 0; kk < 64; kk += 32) {
      bf16x8 af[4], bw[4];
#pragma unroll
      for (int mi = 0; mi < 4; mi++)
        af[mi] = *(const bf16x8*)&As[(wr + mi * 16 + lrow) * 64 + kk + lk8];
#pragma unroll
      for (int ni = 0; ni < 4; ni++)
        bw[ni] = *(const bf16x8*)&Bs[(wc + ni * 16 + lrow) * 64 + kk + lk8];
#pragma unroll
      for (int mi = 0; mi < 4; mi++)
#pragma unroll
        for (int ni = 0; ni < 4; ni++)
          acc[mi][ni] = __builtin_amdgcn_mfma_f32_16x16x32_bf16(
              af[mi], bw[ni], acc[mi][ni], 0, 0, 0);
    }
    __syncthreads();
  }

  const int rb = (lane >> 4) * 4;
  const int cb = lane & 15;
#pragma unroll
  for (int mi = 0; mi < 4; mi++) {
#pragma unroll
    for (int ni = 0; ni < 4; ni++) {
#pragma unroll
      for (int i = 0; i < 4; i++) {
        long m  = m0 + wr + mi * 16 + rb + i;
        long n  = n0 + wc + ni * 16 + cb;
        float v = acc[mi][ni][i];
        if constexpr (MODE == 0) {
          outF[z * out_zs + m * ldout + n] = v + bias[z * bias_zs + n];
        } else if constexpr (MODE == 1) {
          int xz = (int)(m / (B_ * TIN));
          int rr = (int)(m % (B_ * TIN));
          int b  = rr / TIN;
          int t  = rr % TIN;
          outB[(((long)(xz * TIN + t)) * B_ + b) * D_ + n] = f2bf(v + bias[n]);
        } else if constexpr (MODE == 2) {
          outB[m * ldout + n] = f2bf(v);
        } else {
          if (n < 66) {
            int t = (int)(m >> 10);
            int b = (int)(m & 1023);
            outF[(long)b * (TOUT * 66) + t * 66 + n] = v + bias[n];
          }
        }
      }
    }
  }
}

// ---------------------------------------------------------------------------
// LSTM cell elementwise: reads gates[z][b][4H] f32 + c[z][b][H] f32,
// writes c and h(bf16) to up to 3 destinations per z.
// ---------------------------------------------------------------------------
__global__ void cell_k(const float* __restrict__ gates, float* __restrict__ c,
                       unsigned short* p0a, unsigned short* p0b,
                       unsigned short* p0c, unsigned short* p1a,
                       unsigned short* p1b, unsigned short* p1c) {
  const int z   = blockIdx.z;
  const long idx = (long)blockIdx.x * blockDim.x + threadIdx.x;  // < B*H
  const int b = (int)(idx >> 10);
  const int j = (int)(idx & 1023);
  const float* g = gates + (long)z * B_ * G_ + (long)b * G_;
  float gi = g[j], gf = g[j + 1024], gg = g[j + 2048], go = g[j + 3072];
  float* cp = c + (long)z * B_ * H_ + idx;
  float si = 1.f / (1.f + __expf(-gi));
  float sf = 1.f / (1.f + __expf(-gf));
  float so = 1.f / (1.f + __expf(-go));
  float cc = sf * cp[0] + si * tanhf(gg);
  cp[0] = cc;
  unsigned short hb = f2bf(so * tanhf(cc));
  unsigned short* pa = z ? p1a : p0a;
  unsigned short* pb = z ? p1b : p0b;
  unsigned short* pc = z ? p1c : p0c;
  if (pa) pa[idx] = hb;
  if (pb) pb[idx] = hb;
  if (pc) pc[idx] = hb;
}

// ---------------------------------------------------------------------------
// Attention: block per batch row b. scores[s] = <cat_h[s,b,:], c[b,:]>,
// softmax over 21, atth[b,:] = sum_s attn[s] * cat_h[s,b,:].
// ---------------------------------------------------------------------------
__launch_bounds__(256)
__global__ void attn_k(const unsigned short* __restrict__ cath,
                       const float* __restrict__ c,
                       unsigned short* __restrict__ atth) {
  const int b   = blockIdx.x;
  const int tid = threadIdx.x;
  const float* cb = c + (long)b * H_;
  float cj[4];
#pragma unroll
  for (int u = 0; u < 4; u++) cj[u] = cb[tid + 256 * u];
  float ps[21];
#pragma unroll
  for (int s = 0; s < 21; s++) {
    const unsigned short* hb = cath + ((long)s * B_ + b) * H_;
    float a = 0.f;
#pragma unroll
    for (int u = 0; u < 4; u++) a += bf2f(hb[tid + 256 * u]) * cj[u];
    ps[s] = a;
  }
#pragma unroll
  for (int s = 0; s < 21; s++) {
#pragma unroll
    for (int off = 32; off; off >>= 1) ps[s] += __shfl_down(ps[s], off);
  }
  __shared__ float sred[21][4];
  __shared__ float sw[21];
  const int wv = tid >> 6, ln = tid & 63;
  if (ln == 0) {
#pragma unroll
    for (int s = 0; s < 21; s++) sred[s][wv] = ps[s];
  }
  __syncthreads();
  if (tid < 21) sw[tid] = sred[tid][0] + sred[tid][1] + sred[tid][2] + sred[tid][3];
  __syncthreads();
  float mx = -1e30f;
#pragma unroll
  for (int s = 0; s < 21; s++) mx = fmaxf(mx, sw[s]);
  float wsum = 0.f;
  float w[21];
#pragma unroll
  for (int s = 0; s < 21; s++) { w[s] = __expf(sw[s] - mx); wsum += w[s]; }
  float inv = 1.f / wsum;
#pragma unroll
  for (int u = 0; u < 4; u++) {
    int j = tid + 256 * u;
    float a = 0.f;
#pragma unroll
    for (int s = 0; s < 21; s++) a += w[s] * bf2f(cath[((long)s * B_ + b) * H_ + j]);
    atth[(long)b * H_ + j] = f2bf(a * inv);
  }
}

// ---------------------------------------------------------------------------
// Prep: all casts/packs/zeros/bias-combines in one kernel (exact-size grid).
// ---------------------------------------------------------------------------
__global__ void prep_k(const float* __restrict__ x, const float* __restrict__ zin,
                       const float* __restrict__ wf,
                       const float* __restrict__ enc_wih, const float* __restrict__ enc_whh,
                       const float* __restrict__ encp_wih, const float* __restrict__ encp_whh,
                       const float* __restrict__ dec_whh, const float* __restrict__ dec_wih,
                       const float* __restrict__ lin_w, const float* __restrict__ pose_w,
                       const float* __restrict__ enc_bih, const float* __restrict__ enc_bhh,
                       const float* __restrict__ encp_bih, const float* __restrict__ encp_bhh,
                       unsigned short* WcatE, unsigned short* Wdec,
                       unsigned short* dwih_bf, unsigned short* lin_wT,
                       unsigned short* pose_pad, unsigned short* wf_pad,
                       unsigned short* x_pad, unsigned short* h_cur,
                       float* c_enc, float* bias_e) {
  long idx = (long)blockIdx.x * 256 + threadIdx.x;
  const long S0 = 6291456, S1 = 6291456, S2 = 4194304, S3 = 2097152,
             S4 = 524288, S5 = 131072, S6 = 65536, S7 = 2621440,
             S8 = 2097152, S9 = 2097152, S10 = 8192;
  if (idx < S0) {  // Wcat_enc = [enc_whh | enc_wih]
    long r = idx / 1536, cc = idx % 1536;
    float v = (cc < 1024) ? enc_whh[r * 1024 + cc] : enc_wih[r * 512 + cc - 1024];
    WcatE[idx] = f2bf(v);
    return;
  }
  idx -= S0;
  if (idx < S1) {  // Wcat_encp
    long r = idx / 1536, cc = idx % 1536;
    float v = (cc < 1024) ? encp_whh[r * 1024 + cc] : encp_wih[r * 512 + cc - 1024];
    WcatE[S0 + idx] = f2bf(v);
    return;
  }
  idx -= S1;
  if (idx < S2) {  // Wdec cols 0..1023 = dec_whh
    long r = idx / 1024, cc = idx % 1024;
    Wdec[r * 2048 + cc] = f2bf(dec_whh[idx]);
    return;
  }
  idx -= S2;
  if (idx < S3) { dwih_bf[idx] = f2bf(dec_wih[idx]); return; }
  idx -= S3;
  if (idx < S4) {  // lin_wT[h][d] = lin_w[d][h]
    long h = idx / 512, d = idx % 512;
    lin_wT[idx] = f2bf(lin_w[d * 1024 + h]);
    return;
  }
  idx -= S4;
  if (idx < S5) {  // pose_w padded to 128 rows
    long r = idx / 1024, cc = idx % 1024;
    pose_pad[idx] = f2bf(r < 66 ? pose_w[r * 1024 + cc] : 0.f);
    return;
  }
  idx -= S5;
  if (idx < S6) {  // wf padded to 128 cols
    long r = idx / 128, cc = idx % 128;
    wf_pad[idx] = f2bf(cc < 66 ? wf[r * 66 + cc] : 0.f);
    return;
  }
  idx -= S6;
  if (idx < S7) {  // x/z padded: row r = (xz*10240) + b*10 + t
    long r = idx / 128, cc = idx % 128;
    float v = 0.f;
    if (cc < 66) v = (r < 10240) ? x[r * 66 + cc] : zin[(r - 10240) * 66 + cc];
    x_pad[idx] = f2bf(v);
    return;
  }
  idx -= S7;
  if (idx < S8) { h_cur[idx] = 0; return; }
  idx -= S8;
  if (idx < S9) { c_enc[idx] = 0.f; return; }
  idx -= S9;
  if (idx < S10) {
    long zz = idx >> 12, j = idx & 4095;
    bias_e[idx] = zz ? (encp_bih[j] + encp_bhh[j]) : (enc_bih[j] + enc_bhh[j]);
    return;
  }
}

// bias_dec[r] = dec_bih[r] + dec_bhh[r] + sum_k dec_wih[r,k] * lin_b[k]
__global__ void biasd_k(const float* __restrict__ dec_wih,
                        const float* __restrict__ lin_b,
                        const float* __restrict__ dec_bih,
                        const float* __restrict__ dec_bhh,
                        float* __restrict__ bias_d) {
  const int r  = blockIdx.x;
  const int ln = threadIdx.x;  // 64
  const float* row = dec_wih + (long)r * 512;
  float a = 0.f;
  for (int k = ln; k < 512; k += 64) a += row[k] * lin_b[k];
#pragma unroll
  for (int off = 32; off; off >>= 1) a += __shfl_down(a, off);
  if (ln == 0) bias_d[r] = a + dec_bih[r] + dec_bhh[r];
}

// ws_size-insufficient sentinel: fill d_out with (float)ws_size for diagnosis.
__global__ void sentinel_k(float* out, long n, float v) {
  long i = (long)blockIdx.x * 256 + threadIdx.x;
  if (i < n) out[i] = v;
}

// ---------------------------------------------------------------------------
extern "C" void kernel_launch(void* const* d_in, const int* in_sizes, int n_in,
                              void* d_out, int out_size, void* d_ws,
                              size_t ws_size, hipStream_t stream) {
  const float* x        = (const float*)d_in[0];
  const float* zin      = (const float*)d_in[1];
  const float* wf       = (const float*)d_in[2];
  const float* bf       = (const float*)d_in[3];
  const float* enc_wih  = (const float*)d_in[4];
  const float* enc_whh  = (const float*)d_in[5];
  const float* enc_bih  = (const float*)d_in[6];
  const float* enc_bhh  = (const float*)d_in[7];
  const float* encp_wih = (const float*)d_in[8];
  const float* encp_whh = (const float*)d_in[9];
  const float* encp_bih = (const float*)d_in[10];
  const float* encp_bhh = (const float*)d_in[11];
  const float* dec_wih  = (const float*)d_in[12];
  const float* dec_whh  = (const float*)d_in[13];
  const float* dec_bih  = (const float*)d_in[14];
  const float* dec_bhh  = (const float*)d_in[15];
  const float* lin_w    = (const float*)d_in[16];
  const float* lin_b    = (const float*)d_in[17];
  const float* pose_w   = (const float*)d_in[18];
  const float* pose_b   = (const float*)d_in[19];

  char* ws = (char*)d_ws;
  size_t off = 0;
  auto alloc = [&](size_t bytes) {
    void* p = ws + off;
    off += (bytes + 255) & ~(size_t)255;
    return p;
  };
  // --- region A (dead after encoder; hs aliases it in the decoder phase) ---
  size_t regionA_start = off;
  unsigned short* WcatE = (unsigned short*)alloc(2L * 4096 * 1536 * 2);  // 25.2MB
  unsigned short* dwih  = (unsigned short*)alloc(4096L * 512 * 2);       //  4.2MB
  unsigned short* linT  = (unsigned short*)alloc(1024L * 512 * 2);       //  1.0MB
  unsigned short* xpad  = (unsigned short*)alloc(20480L * 128 * 2);      //  5.2MB
  unsigned short* feat  = (unsigned short*)alloc(20L * B_ * D_ * 2);     // 21.0MB
  unsigned short* hs    = (unsigned short*)(ws + regionA_start);         // 52.4MB alias
  // --- persistent region ---
  unsigned short* Wdec  = (unsigned short*)alloc(4096L * 2048 * 2);
  unsigned short* posep = (unsigned short*)alloc(128L * 1024 * 2);
  unsigned short* wfp   = (unsigned short*)alloc(512L * 128 * 2);
  unsigned short* cath  = (unsigned short*)alloc(21L * B_ * H_ * 2);
  unsigned short* hcur  = (unsigned short*)alloc(2L * B_ * H_ * 2);
  float*          cenc  = (float*)alloc(2L * B_ * H_ * 4);
  unsigned short* atth  = (unsigned short*)alloc((long)B_ * H_ * 2);
  float*          gates = (float*)alloc(2L * B_ * G_ * 4);
  float*          biasE = (float*)alloc(2L * G_ * 4);
  float*          biasD = (float*)alloc((long)G_ * 4);

  if (off > ws_size) {
    // Insufficient scratch: DO NOT touch the arena (avoids OOB / container
    // crash). Emit sentinel = ws_size for off-line diagnosis.
    sentinel_k<<<(out_size + 255) / 256, 256, 0, stream>>>(
        (float*)d_out, out_size, (float)ws_size);
    return;
  }

  prep_k<<<103200, 256, 0, stream>>>(x, zin, wf, enc_wih, enc_whh, encp_wih,
                                     encp_whh, dec_whh, dec_wih, lin_w, pose_w,
                                     enc_bih, enc_bhh, encp_bih, encp_bhh,
                                     WcatE, Wdec, dwih, linT, posep, wfp, xpad,
                                     hcur, cenc, biasE);
  biasd_k<<<4096, 64, 0, stream>>>(dec_wih, lin_b, dec_bih, dec_bhh, biasD);

  // W2 = dec_wih @ lin_w -> Wdec cols 1024..2047
  gemm_k<2><<<dim3(32, 8, 1), 256, 0, stream>>>(
      dwih, nullptr, 512, 512, 512, 512, linT, 512, nullptr, nullptr,
      Wdec + 1024, 2048, 0, 0, 0, 0, 0);

  // feat = [x;z]_pad @ wf_pad.T + bf
  gemm_k<1><<<dim3(160, 4, 1), 256, 0, stream>>>(
      xpad, nullptr, 128, 128, 128, 128, wfp, 128, bf, nullptr, feat, 512,
      0, 0, 0, 0, 0);

  // encoders (z=0: enc, z=1: enc_post), grouped in one launch per step
  for (int t = 0; t < TIN; t++) {
    gemm_k<0><<<dim3(8, 32, 2), 256, 0, stream>>>(
        hcur, feat + (long)t * B_ * D_, 1024, 512, 1536, 1024, WcatE, 1536,
        biasE, gates, nullptr, 4096,
        (long)B_ * H_, (long)TIN * B_ * D_, 4096L * 1536, 4096,
        (long)B_ * G_);
    cell_k<<<dim3(4096, 1, 2), 256, 0, stream>>>(
        gates, cenc,
        cath + (long)t * B_ * H_, hcur,
        (t == TIN - 1) ? (cath + 10L * B_ * H_) : nullptr,
        cath + (long)(11 + t) * B_ * H_, hcur + (long)B_ * H_, nullptr);
  }

  // decoder
  for (int d = 0; d < TOUT; d++) {
    attn_k<<<1024, 256, 0, stream>>>(cath, cenc, atth);
    gemm_k<0><<<dim3(8, 32, 1), 256, 0, stream>>>(
        atth, cath + 10L * B_ * H_, 1024, 1024, 2048, 1024, Wdec, 2048, biasD,
        gates, nullptr, 4096, 0, 0, 0, 0, 0);
    cell_k<<<dim3(4096, 1, 1), 256, 0, stream>>>(
        gates, cenc,
        cath + 10L * B_ * H_, hs + (long)d * B_ * H_, nullptr,
        nullptr, nullptr, nullptr);
  }

  // out[b,t,p] = hs[t,b,:] @ pose_w.T + pose_b
  gemm_k<3><<<dim3(200, 1, 1), 256, 0, stream>>>(
      hs, nullptr, 1024, 1024, 1024, 1024, posep, 1024, pose_b, (float*)d_out,
      nullptr, 0, 0, 0, 0, 0, 0);
}

// Round 10
// 2177.436 us; speedup vs baseline: 1.3377x; 1.3377x over previous
//
#include <hip/hip_runtime.h>
#include <cstdint>

// ---------------------------------------------------------------------------
// Seq2seq LSTM attention model, MI355X bf16-MFMA implementation.
//
// Round-3 structure: LSTM cell fused into the gates-GEMM epilogue via a
// gate-interleaved W row permutation (wave's 64 cols = 4 gates x 16 units,
// fragment ni = gate, lane cb = unit -> cell computed entirely in-register).
// h state double-buffered by step parity (GEMM reads h[par], epilogue writes
// h[par^1]) to avoid cross-block read/write races.
//
//   prep:   vec8 cast/pack weights to bf16 (permuted rows for gate interleave)
//   b2:     bias_dec[pos(r)] = dec_bih + dec_bhh + dec_wih @ lin_b
//   W2:     GEMM dec_wih @ lin_w -> Wdec cols 1024..2047 at permuted rows
//   feat:   GEMM [x;z]_pad @ wf_pad.T + bf -> feat[xz][t][b][d] bf16
//   enc:    10x grouped (z=2) fused GEMM+cell  [h ; x_t] @ Wcat.T
//   dec:    25x { attn -> atth ; fused GEMM+cell [atth ; h_n] @ Wdec.T }
//   pose:   GEMM hs @ pose_w_pad.T + pose_b -> d_out (f32 [B,25,66])
// ---------------------------------------------------------------------------

#define B_   1024
#define H_   1024
#define D_   512
#define G_   4096
#define TIN  10
#define TOUT 25
#define BH   (B_ * H_)

typedef __bf16 bf16x8 __attribute__((ext_vector_type(8)));
typedef float  f32x4  __attribute__((ext_vector_type(4)));
typedef unsigned short ushort8v __attribute__((ext_vector_type(8)));

__device__ __forceinline__ unsigned short f2bf(float f) {
  unsigned int x = __builtin_bit_cast(unsigned int, f);
  x += 0x7fffu + ((x >> 16) & 1u);        // RNE
  return (unsigned short)(x >> 16);
}
__device__ __forceinline__ float bf2f(unsigned short u) {
  unsigned int x = ((unsigned int)u) << 16;
  return __builtin_bit_cast(float, x);
}

// gate-interleave permutation: interleaved row n <-> original row g*1024+u
__device__ __forceinline__ int gate_orig(int n) {
  int g = (n >> 4) & 3;
  int u = ((n >> 7) << 5) | (((n >> 6) & 1) << 4) | (n & 15);
  return (g << 10) | u;
}
__device__ __forceinline__ int gate_pos(int r) {
  int g = r >> 10, u = r & 1023;
  return ((u >> 5) << 7) | (((u >> 4) & 1) << 6) | (g << 4) | (u & 15);
}

__device__ __forceinline__ void gload16(const void* g, void* l) {
  __builtin_amdgcn_global_load_lds(
      (const __attribute__((address_space(1))) void*)g,
      (__attribute__((address_space(3))) void*)l, 16, 0, 0);
}

__device__ __forceinline__ void cvt8(const float* __restrict__ s,
                                     unsigned short* __restrict__ d) {
  float4 a = ((const float4*)s)[0];
  float4 b = ((const float4*)s)[1];
  ushort8v o;
  o[0] = f2bf(a.x); o[1] = f2bf(a.y); o[2] = f2bf(a.z); o[3] = f2bf(a.w);
  o[4] = f2bf(b.x); o[5] = f2bf(b.y); o[6] = f2bf(b.z); o[7] = f2bf(b.w);
  *(ushort8v*)d = o;
}

// ---------------------------------------------------------------------------
// Plain GEMM (non-cell outputs): C[m,n] = sum_k A[m,k] * W[n,k] (+bias).
// MODE 1: bf16 out remapped to feat layout. MODE 2: bf16 out to permuted
// Wdec rows. MODE 3: pose output (n<66, f32, [B,25,66]).
// ---------------------------------------------------------------------------
template <int MODE>
__launch_bounds__(256, 2)
__global__ void gemm_k(const unsigned short* __restrict__ A1, int lda1, int K,
                       const unsigned short* __restrict__ W, int ldw,
                       const float* __restrict__ bias,
                       float* __restrict__ outF,
                       unsigned short* __restrict__ outB, int ldout) {
  __shared__ __align__(16) unsigned short As[128 * 64];
  __shared__ __align__(16) unsigned short Bs[128 * 64];
  const int tid  = threadIdx.x;
  const int lane = tid & 63;
  const int wave = tid >> 6;
  const long m0  = (long)blockIdx.x * 128;
  const long n0  = (long)blockIdx.y * 128;
  const int wr   = (wave >> 1) * 64;
  const int wc   = (wave & 1) * 64;
  const int lrow = lane & 15;
  const int lk8  = (lane >> 4) * 8;

  f32x4 acc[4][4];
#pragma unroll
  for (int i = 0; i < 4; i++)
#pragma unroll
    for (int j = 0; j < 4; j++) acc[i][j] = f32x4{0.f, 0.f, 0.f, 0.f};

  for (int k0 = 0; k0 < K; k0 += 64) {
#pragma unroll
    for (int i = 0; i < 4; i++) {
      int c  = i * 256 + tid;
      int r  = c >> 3;
      int c8 = (c & 7) * 8;
      gload16(A1 + (m0 + r) * (long)lda1 + k0 + c8, &As[c * 8]);
      gload16(W + (n0 + r) * (long)ldw + k0 + c8, &Bs[c * 8]);
    }
    __syncthreads();
#pragma unroll
    for (int kk = 0; kk < 64; kk += 32) {
      bf16x8 af[4], bw[4];
#pragma unroll
      for (int mi = 0; mi < 4; mi++)
        af[mi] = *(const bf16x8*)&As[(wr + mi * 16 + lrow) * 64 + kk + lk8];
#pragma unroll
      for (int ni = 0; ni < 4; ni++)
        bw[ni] = *(const bf16x8*)&Bs[(wc + ni * 16 + lrow) * 64 + kk + lk8];
#pragma unroll
      for (int mi = 0; mi < 4; mi++)
#pragma unroll
        for (int ni = 0; ni < 4; ni++)
          acc[mi][ni] = __builtin_amdgcn_mfma_f32_16x16x32_bf16(
              af[mi], bw[ni], acc[mi][ni], 0, 0, 0);
    }
    __syncthreads();
  }

  const int rb = (lane >> 4) * 4;
  const int cb = lane & 15;
#pragma unroll
  for (int mi = 0; mi < 4; mi++) {
#pragma unroll
    for (int ni = 0; ni < 4; ni++) {
#pragma unroll
      for (int i = 0; i < 4; i++) {
        long m  = m0 + wr + mi * 16 + rb + i;
        long n  = n0 + wc + ni * 16 + cb;
        float v = acc[mi][ni][i];
        if constexpr (MODE == 1) {
          int xz = (int)(m / (B_ * TIN));
          int rr = (int)(m % (B_ * TIN));
          int b  = rr / TIN;
          int t  = rr % TIN;
          outB[(((long)(xz * TIN + t)) * B_ + b) * D_ + n] = f2bf(v + bias[n]);
        } else if constexpr (MODE == 2) {
          outB[(long)gate_pos((int)m) * ldout + n] = f2bf(v);
        } else {
          if (n < 66) {
            int t = (int)(m >> 10);
            int b = (int)(m & 1023);
            outF[(long)b * (TOUT * 66) + t * 66 + n] = v + bias[n];
          }
        }
      }
    }
  }
}

// ---------------------------------------------------------------------------
// Fused gates-GEMM + LSTM cell. W rows gate-interleaved; each wave's 64 cols
// = gates i,f,g,o (fragment ni) x 16 units (lane cb). Epilogue computes
// c_new/h fully in-register. grid (8, 32, nz). Writes c in place (exclusive
// per (m,unit)) and h (bf16) to up to 3 dests per z.
// ---------------------------------------------------------------------------
__launch_bounds__(256, 2)
__global__ void gemm_cell_k(const unsigned short* __restrict__ A1,
                            const unsigned short* __restrict__ A2,
                            int lda1, int lda2, int K, int K1,
                            const unsigned short* __restrict__ W, int ldw,
                            const float* __restrict__ bias,
                            float* __restrict__ cst,
                            unsigned short* p0a, unsigned short* p0b,
                            unsigned short* p0c, unsigned short* p1a,
                            unsigned short* p1b, unsigned short* p1c,
                            long a1_zs, long a2_zs, long w_zs, long bias_zs) {
  __shared__ __align__(16) unsigned short As[128 * 64];
  __shared__ __align__(16) unsigned short Bs[128 * 64];
  const int tid  = threadIdx.x;
  const int lane = tid & 63;
  const int wave = tid >> 6;
  const int z    = blockIdx.z;
  const long m0  = (long)blockIdx.x * 128;
  const long n0  = (long)blockIdx.y * 128;
  const int wr   = (wave >> 1) * 64;
  const int wc   = (wave & 1) * 64;
  const int lrow = lane & 15;
  const int lk8  = (lane >> 4) * 8;

  f32x4 acc[4][4];
#pragma unroll
  for (int i = 0; i < 4; i++)
#pragma unroll
    for (int j = 0; j < 4; j++) acc[i][j] = f32x4{0.f, 0.f, 0.f, 0.f};

  const unsigned short* Wz  = W + (long)z * w_zs;
  const unsigned short* A1z = A1 + (long)z * a1_zs;
  const unsigned short* A2z = A2 + (long)z * a2_zs;

  for (int k0 = 0; k0 < K; k0 += 64) {
    const unsigned short* asrc;
    int ald, ak;
    if (k0 < K1) { asrc = A1z; ald = lda1; ak = k0; }
    else         { asrc = A2z; ald = lda2; ak = k0 - K1; }
#pragma unroll
    for (int i = 0; i < 4; i++) {
      int c  = i * 256 + tid;
      int r  = c >> 3;
      int c8 = (c & 7) * 8;
      gload16(asrc + (m0 + r) * (long)ald + ak + c8, &As[c * 8]);
      gload16(Wz + (n0 + r) * (long)ldw + k0 + c8, &Bs[c * 8]);
    }
    __syncthreads();
#pragma unroll
    for (int kk = 0; kk < 64; kk += 32) {
      bf16x8 af[4], bw[4];
#pragma unroll
      for (int mi = 0; mi < 4; mi++)
        af[mi] = *(const bf16x8*)&As[(wr + mi * 16 + lrow) * 64 + kk + lk8];
#pragma unroll
      for (int ni = 0; ni < 4; ni++)
        bw[ni] = *(const bf16x8*)&Bs[(wc + ni * 16 + lrow) * 64 + kk + lk8];
#pragma unroll
      for (int mi = 0; mi < 4; mi++)
#pragma unroll
        for (int ni = 0; ni < 4; ni++)
          acc[mi][ni] = __builtin_amdgcn_mfma_f32_16x16x32_bf16(
              af[mi], bw[ni], acc[mi][ni], 0, 0, 0);
    }
    __syncthreads();
  }

  // ---- fused cell epilogue -------------------------------------------------
  const int rb = (lane >> 4) * 4;
  const int cb = lane & 15;
  const int j  = (int)(n0 >> 2) + ((wave & 1) << 4) + cb;  // unit index
  const long bz = bias_zs * z + n0 + wc + cb;
  const float b0 = bias[bz];
  const float b1 = bias[bz + 16];
  const float b2 = bias[bz + 32];
  const float b3 = bias[bz + 48];
  unsigned short* pa = z ? p1a : p0a;
  unsigned short* pb = z ? p1b : p0b;
  unsigned short* pc = z ? p1c : p0c;
  float* cz = cst + (long)z * BH;
#pragma unroll
  for (int mi = 0; mi < 4; mi++) {
#pragma unroll
    for (int i = 0; i < 4; i++) {
      long m  = m0 + wr + mi * 16 + rb + i;
      float gi = acc[mi][0][i] + b0;
      float gf = acc[mi][1][i] + b1;
      float gg = acc[mi][2][i] + b2;
      float go = acc[mi][3][i] + b3;
      float si = 1.f / (1.f + __expf(-gi));
      float sf = 1.f / (1.f + __expf(-gf));
      float so = 1.f / (1.f + __expf(-go));
      float tg = 1.f - 2.f / (__expf(2.f * gg) + 1.f);
      long ci  = m * H_ + j;
      float cc = sf * cz[ci] + si * tg;
      cz[ci]   = cc;
      float tc = 1.f - 2.f / (__expf(2.f * cc) + 1.f);
      unsigned short hb = f2bf(so * tc);
      if (pa) pa[ci] = hb;
      if (pb) pb[ci] = hb;
      if (pc) pc[ci] = hb;
    }
  }
}

// ---------------------------------------------------------------------------
// Attention: block per batch row b. Vectorized ushort4 loads; 21 K/V tiles
// cached in registers (single cath pass). Slot 10 (h_n) is a separate ptr
// (double-buffered by decoder parity).
// ---------------------------------------------------------------------------
__launch_bounds__(256)
__global__ void attn_k(const unsigned short* __restrict__ cath,
                       const unsigned short* __restrict__ hn,
                       const float* __restrict__ c,
                       unsigned short* __restrict__ atth) {
  const int b   = blockIdx.x;
  const int tid = threadIdx.x;
  const int j4  = tid * 4;
  float4 cj = *(const float4*)(c + (long)b * H_ + j4);
  ushort4 kv[21];
  float ps[21];
#pragma unroll
  for (int s = 0; s < 21; s++) {
    const unsigned short* src =
        (s == 10) ? (hn + (long)b * H_) : (cath + ((long)s * B_ + b) * H_);
    ushort4 v = *(const ushort4*)(src + j4);
    kv[s] = v;
    ps[s] = bf2f(v.x) * cj.x + bf2f(v.y) * cj.y + bf2f(v.z) * cj.z +
            bf2f(v.w) * cj.w;
  }
#pragma unroll
  for (int s = 0; s < 21; s++) {
#pragma unroll
    for (int off = 32; off; off >>= 1) ps[s] += __shfl_down(ps[s], off);
  }
  __shared__ float sred[21][4];
  __shared__ float sw[21];
  const int wv = tid >> 6, ln = tid & 63;
  if (ln == 0) {
#pragma unroll
    for (int s = 0; s < 21; s++) sred[s][wv] = ps[s];
  }
  __syncthreads();
  if (tid < 21) sw[tid] = sred[tid][0] + sred[tid][1] + sred[tid][2] + sred[tid][3];
  __syncthreads();
  float mx = -1e30f;
#pragma unroll
  for (int s = 0; s < 21; s++) mx = fmaxf(mx, sw[s]);
  float wsum = 0.f;
  float w[21];
#pragma unroll
  for (int s = 0; s < 21; s++) { w[s] = __expf(sw[s] - mx); wsum += w[s]; }
  float inv = 1.f / wsum;
  float4 o = {0.f, 0.f, 0.f, 0.f};
#pragma unroll
  for (int s = 0; s < 21; s++) {
    o.x += w[s] * bf2f(kv[s].x);
    o.y += w[s] * bf2f(kv[s].y);
    o.z += w[s] * bf2f(kv[s].z);
    o.w += w[s] * bf2f(kv[s].w);
  }
  ushort4 ov;
  ov.x = f2bf(o.x * inv); ov.y = f2bf(o.y * inv);
  ov.z = f2bf(o.z * inv); ov.w = f2bf(o.w * inv);
  *(ushort4*)(atth + (long)b * H_ + j4) = ov;
}

// ---------------------------------------------------------------------------
// Prep (vec8): each thread handles 8 contiguous elements. Weight rows are
// written at gate-interleaved positions (gate_orig).
// ---------------------------------------------------------------------------
__global__ void prep_k(const float* __restrict__ x, const float* __restrict__ zin,
                       const float* __restrict__ wf,
                       const float* __restrict__ enc_wih, const float* __restrict__ enc_whh,
                       const float* __restrict__ encp_wih, const float* __restrict__ encp_whh,
                       const float* __restrict__ dec_whh, const float* __restrict__ dec_wih,
                       const float* __restrict__ lin_w, const float* __restrict__ pose_w,
                       const float* __restrict__ enc_bih, const float* __restrict__ enc_bhh,
                       const float* __restrict__ encp_bih, const float* __restrict__ encp_bhh,
                       unsigned short* WcatE, unsigned short* Wdec,
                       unsigned short* dwih_bf, unsigned short* lin_wT,
                       unsigned short* pose_pad, unsigned short* wf_pad,
                       unsigned short* x_pad, unsigned short* h_e,
                       float* c_enc, float* bias_e) {
  long v = (long)blockIdx.x * 256 + threadIdx.x;
  if (v < 786432) {  // WcatE z0 = [enc_whh | enc_wih], permuted rows
    int n = (int)(v / 192), k8 = (int)(v % 192) * 8;
    int ro = gate_orig(n);
    const float* s = (k8 < 1024) ? enc_whh + (long)ro * 1024 + k8
                                 : enc_wih + (long)ro * 512 + (k8 - 1024);
    cvt8(s, WcatE + (long)n * 1536 + k8);
    return;
  }
  v -= 786432;
  if (v < 786432) {  // WcatE z1
    int n = (int)(v / 192), k8 = (int)(v % 192) * 8;
    int ro = gate_orig(n);
    const float* s = (k8 < 1024) ? encp_whh + (long)ro * 1024 + k8
                                 : encp_wih + (long)ro * 512 + (k8 - 1024);
    cvt8(s, WcatE + 6291456L + (long)n * 1536 + k8);
    return;
  }
  v -= 786432;
  if (v < 524288) {  // Wdec cols 0..1023 = dec_whh, permuted rows
    int n = (int)(v / 128), k8 = (int)(v % 128) * 8;
    cvt8(dec_whh + (long)gate_orig(n) * 1024 + k8, Wdec + (long)n * 2048 + k8);
    return;
  }
  v -= 524288;
  if (v < 262144) {  // dwih copy (GEMM A operand, original row order)
    long e = v * 8;
    cvt8(dec_wih + e, dwih_bf + e);
    return;
  }
  v -= 262144;
  if (v < 65536) {  // lin_wT[h][d] = lin_w[d][h]
    int h = (int)(v / 64), d8 = (int)(v % 64) * 8;
    ushort8v o;
#pragma unroll
    for (int q = 0; q < 8; q++) o[q] = f2bf(lin_w[(long)(d8 + q) * 1024 + h]);
    *(ushort8v*)(lin_wT + (long)h * 512 + d8) = o;
    return;
  }
  v -= 65536;
  if (v < 16384) {  // pose_w padded to 128 rows
    int r = (int)(v / 128), c8 = (int)(v % 128) * 8;
    if (r < 66) {
      cvt8(pose_w + (long)r * 1024 + c8, pose_pad + (long)r * 1024 + c8);
    } else {
      ushort8v o;
#pragma unroll
      for (int q = 0; q < 8; q++) o[q] = 0;
      *(ushort8v*)(pose_pad + (long)r * 1024 + c8) = o;
    }
    return;
  }
  v -= 16384;
  if (v < 8192) {  // wf padded to 128 cols
    int r = (int)(v / 16), c8 = (int)(v % 16) * 8;
    ushort8v o;
#pragma unroll
    for (int q = 0; q < 8; q++) {
      int cc = c8 + q;
      o[q] = (cc < 66) ? f2bf(wf[(long)r * 66 + cc]) : 0;
    }
    *(ushort8v*)(wf_pad + (long)r * 128 + c8) = o;
    return;
  }
  v -= 8192;
  if (v < 327680) {  // x/z padded: row r = xz*10240 + b*10 + t
    int r = (int)(v / 16), c8 = (int)(v % 16) * 8;
    ushort8v o;
#pragma unroll
    for (int q = 0; q < 8; q++) {
      int cc = c8 + q;
      float val = 0.f;
      if (cc < 66)
        val = (r < 10240) ? x[(long)r * 66 + cc] : zin[(long)(r - 10240) * 66 + cc];
      o[q] = f2bf(val);
    }
    *(ushort8v*)(x_pad + (long)r * 128 + c8) = o;
    return;
  }
  v -= 327680;
  if (v < 262144) {  // h_e parity-0 zeros (2 z slots)
    ushort8v o;
#pragma unroll
    for (int q = 0; q < 8; q++) o[q] = 0;
    *(ushort8v*)(h_e + v * 8) = o;
    return;
  }
  v -= 262144;
  if (v < 262144) {  // c_enc zeros
    float4 z4 = {0.f, 0.f, 0.f, 0.f};
    ((float4*)(c_enc + v * 8))[0] = z4;
    ((float4*)(c_enc + v * 8))[1] = z4;
    return;
  }
  v -= 262144;
  if (v < 1024) {  // bias_e permuted
    long e = v * 8;
#pragma unroll
    for (int q = 0; q < 8; q++) {
      long idx = e + q;
      int zz = (int)(idx >> 12);
      int ro = gate_orig((int)(idx & 4095));
      bias_e[idx] = zz ? (encp_bih[ro] + encp_bhh[ro])
                       : (enc_bih[ro] + enc_bhh[ro]);
    }
    return;
  }
}

// bias_dec[pos(r)] = dec_bih[r] + dec_bhh[r] + dec_wih[r,:] @ lin_b
__global__ void biasd_k(const float* __restrict__ dec_wih,
                        const float* __restrict__ lin_b,
                        const float* __restrict__ dec_bih,
                        const float* __restrict__ dec_bhh,
                        float* __restrict__ bias_d) {
  const int r  = blockIdx.x;
  const int ln = threadIdx.x;  // 64
  const float* row = dec_wih + (long)r * 512;
  float a = 0.f;
  for (int k = ln; k < 512; k += 64) a += row[k] * lin_b[k];
#pragma unroll
  for (int off = 32; off; off >>= 1) a += __shfl_down(a, off);
  if (ln == 0) bias_d[gate_pos(r)] = a + dec_bih[r] + dec_bhh[r];
}

// ws_size-insufficient sentinel: fill d_out with (float)ws_size for diagnosis.
__global__ void sentinel_k(float* out, long n, float v) {
  long i = (long)blockIdx.x * 256 + threadIdx.x;
  if (i < n) out[i] = v;
}

// ---------------------------------------------------------------------------
extern "C" void kernel_launch(void* const* d_in, const int* in_sizes, int n_in,
                              void* d_out, int out_size, void* d_ws,
                              size_t ws_size, hipStream_t stream) {
  const float* x        = (const float*)d_in[0];
  const float* zin      = (const float*)d_in[1];
  const float* wf       = (const float*)d_in[2];
  const float* bf       = (const float*)d_in[3];
  const float* enc_wih  = (const float*)d_in[4];
  const float* enc_whh  = (const float*)d_in[5];
  const float* enc_bih  = (const float*)d_in[6];
  const float* enc_bhh  = (const float*)d_in[7];
  const float* encp_wih = (const float*)d_in[8];
  const float* encp_whh = (const float*)d_in[9];
  const float* encp_bih = (const float*)d_in[10];
  const float* encp_bhh = (const float*)d_in[11];
  const float* dec_wih  = (const float*)d_in[12];
  const float* dec_whh  = (const float*)d_in[13];
  const float* dec_bih  = (const float*)d_in[14];
  const float* dec_bhh  = (const float*)d_in[15];
  const float* lin_w    = (const float*)d_in[16];
  const float* lin_b    = (const float*)d_in[17];
  const float* pose_w   = (const float*)d_in[18];
  const float* pose_b   = (const float*)d_in[19];

  char* ws = (char*)d_ws;
  size_t off = 0;
  auto alloc = [&](size_t bytes) {
    void* p = ws + off;
    off += (bytes + 255) & ~(size_t)255;
    return p;
  };
  // --- region A (dead after encoder; hs aliases its start in decoder) ------
  size_t regionA_start = off;
  unsigned short* WcatE = (unsigned short*)alloc(2L * 4096 * 1536 * 2);  // 25.2MB
  unsigned short* dwih  = (unsigned short*)alloc(4096L * 512 * 2);       //  4.2MB
  unsigned short* linT  = (unsigned short*)alloc(1024L * 512 * 2);       //  1.0MB
  unsigned short* xpad  = (unsigned short*)alloc(20480L * 128 * 2);      //  5.2MB
  unsigned short* feat  = (unsigned short*)alloc(20L * B_ * D_ * 2);     // 21.0MB
  unsigned short* h_e   = (unsigned short*)alloc(4L * BH * 2);  // [par][z] 8.4MB
  unsigned short* hs    = (unsigned short*)(ws + regionA_start);         // 52.4MB alias
  // --- persistent region ---------------------------------------------------
  unsigned short* Wdec  = (unsigned short*)alloc(4096L * 2048 * 2);      // 16.8MB
  unsigned short* posep = (unsigned short*)alloc(128L * 1024 * 2);
  unsigned short* wfp   = (unsigned short*)alloc(512L * 128 * 2);
  unsigned short* cath  = (unsigned short*)alloc(21L * BH * 2);          // 44.0MB
  unsigned short* hd    = (unsigned short*)alloc(2L * BH * 2);  // [par]   4.2MB
  float*          cenc  = (float*)alloc(2L * BH * 4);                    //  8.4MB
  unsigned short* atth  = (unsigned short*)alloc((long)BH * 2);
  float*          biasE = (float*)alloc(2L * G_ * 4);
  float*          biasD = (float*)alloc((long)G_ * 4);

  if (off > ws_size) {
    sentinel_k<<<(out_size + 255) / 256, 256, 0, stream>>>(
        (float*)d_out, out_size, (float)ws_size);
    return;
  }

  prep_k<<<12900, 256, 0, stream>>>(x, zin, wf, enc_wih, enc_whh, encp_wih,
                                    encp_whh, dec_whh, dec_wih, lin_w, pose_w,
                                    enc_bih, enc_bhh, encp_bih, encp_bhh,
                                    WcatE, Wdec, dwih, linT, posep, wfp, xpad,
                                    h_e, cenc, biasE);
  biasd_k<<<4096, 64, 0, stream>>>(dec_wih, lin_b, dec_bih, dec_bhh, biasD);

  // W2 = dec_wih @ lin_w -> Wdec cols 1024..2047 (permuted rows)
  gemm_k<2><<<dim3(32, 8, 1), 256, 0, stream>>>(
      dwih, 512, 512, linT, 512, nullptr, nullptr, Wdec + 1024, 2048);

  // feat = [x;z]_pad @ wf_pad.T + bf
  gemm_k<1><<<dim3(160, 4, 1), 256, 0, stream>>>(
      xpad, 128, 128, wfp, 128, bf, nullptr, feat, 512);

  // encoders (z=0: enc, z=1: enc_post), fused GEMM+cell, h double-buffered
  for (int t = 0; t < TIN; t++) {
    unsigned short* hr = h_e + (long)(t & 1) * 2 * BH;        // read parity
    unsigned short* hw = h_e + (long)((t + 1) & 1) * 2 * BH;  // write parity
    gemm_cell_k<<<dim3(8, 32, 2), 256, 0, stream>>>(
        hr, feat + (long)t * B_ * D_, 1024, 512, 1536, 1024, WcatE, 1536,
        biasE, cenc,
        /*z0*/ hw, cath + (long)t * BH, (t == TIN - 1) ? hd : nullptr,
        /*z1*/ hw + BH, cath + (long)(11 + t) * BH, nullptr,
        (long)BH, (long)TIN * B_ * D_, 4096L * 1536, (long)G_);
  }

  // decoder: h_n double-buffered in hd[par]; c state continues in cenc[z=0]
  for (int d = 0; d < TOUT; d++) {
    unsigned short* hr = hd + (long)(d & 1) * BH;
    unsigned short* hw = hd + (long)((d + 1) & 1) * BH;
    attn_k<<<1024, 256, 0, stream>>>(cath, hr, cenc, atth);
    gemm_cell_k<<<dim3(8, 32, 1), 256, 0, stream>>>(
        atth, hr, 1024, 1024, 2048, 1024, Wdec, 2048, biasD, cenc,
        hw, hs + (long)d * BH, nullptr, nullptr, nullptr, nullptr,
        0, 0, 0, 0);
  }

  // out[b,t,p] = hs[t,b,:] @ pose_w.T + pose_b
  gemm_k<3><<<dim3(200, 1, 1), 256, 0, stream>>>(
      hs, 1024, 1024, posep, 1024, pose_b, (float*)d_out, nullptr, 0);
}

// Round 11
// 1756.294 us; speedup vs baseline: 1.6585x; 1.2398x over previous
//
#include <hip/hip_runtime.h>
#include <cstdint>

// ---------------------------------------------------------------------------
// Seq2seq LSTM attention model, MI355X bf16-MFMA implementation.
//
// Round-11: (a) gemm_cell_k tile BM 128->64 (grid 2x blocks -> 2 blocks/CU
// decoder, 4/CU encoder; was 1/CU = 9.6% occupancy, latency-bound), (b) XOR
// block-swizzle on LDS tiles (write side: pre-swizzled GLOBAL source, LDS
// dest stays linear per global_load_lds rule; read side: g^(row&7)) to kill
// the 6.29M/dispatch 16-lane-on-4-bank ds_read_b128 conflicts.
//
// Structure (validated round 10: pass, absmax 2.4e-4):
//   prep:   vec8 cast/pack weights to bf16 (gate-interleaved rows)
//   b2:     bias_dec[pos(r)] = dec_bih + dec_bhh + dec_wih @ lin_b
//   W2:     GEMM dec_wih @ lin_w -> Wdec cols 1024..2047 at permuted rows
//   feat:   GEMM [x;z]_pad @ wf_pad.T + bf -> feat[xz][t][b][d] bf16
//   enc:    10x grouped (z=2) fused GEMM+cell  [h ; x_t] @ Wcat.T
//   dec:    25x { attn -> atth ; fused GEMM+cell [atth ; h_n] @ Wdec.T }
//   pose:   GEMM hs @ pose_w_pad.T + pose_b -> d_out (f32 [B,25,66])
// ---------------------------------------------------------------------------

#define B_   1024
#define H_   1024
#define D_   512
#define G_   4096
#define TIN  10
#define TOUT 25
#define BH   (B_ * H_)

typedef __bf16 bf16x8 __attribute__((ext_vector_type(8)));
typedef float  f32x4  __attribute__((ext_vector_type(4)));
typedef unsigned short ushort8v __attribute__((ext_vector_type(8)));

__device__ __forceinline__ unsigned short f2bf(float f) {
  unsigned int x = __builtin_bit_cast(unsigned int, f);
  x += 0x7fffu + ((x >> 16) & 1u);        // RNE
  return (unsigned short)(x >> 16);
}
__device__ __forceinline__ float bf2f(unsigned short u) {
  unsigned int x = ((unsigned int)u) << 16;
  return __builtin_bit_cast(float, x);
}

// gate-interleave permutation: interleaved row n <-> original row g*1024+u
__device__ __forceinline__ int gate_orig(int n) {
  int g = (n >> 4) & 3;
  int u = ((n >> 7) << 5) | (((n >> 6) & 1) << 4) | (n & 15);
  return (g << 10) | u;
}
__device__ __forceinline__ int gate_pos(int r) {
  int g = r >> 10, u = r & 1023;
  return ((u >> 5) << 7) | (((u >> 4) & 1) << 6) | (g << 4) | (u & 15);
}

__device__ __forceinline__ void gload16(const void* g, void* l) {
  __builtin_amdgcn_global_load_lds(
      (const __attribute__((address_space(1))) void*)g,
      (__attribute__((address_space(3))) void*)l, 16, 0, 0);
}

__device__ __forceinline__ void cvt8(const float* __restrict__ s,
                                     unsigned short* __restrict__ d) {
  float4 a = ((const float4*)s)[0];
  float4 b = ((const float4*)s)[1];
  ushort8v o;
  o[0] = f2bf(a.x); o[1] = f2bf(a.y); o[2] = f2bf(a.z); o[3] = f2bf(a.w);
  o[4] = f2bf(b.x); o[5] = f2bf(b.y); o[6] = f2bf(b.z); o[7] = f2bf(b.w);
  *(ushort8v*)d = o;
}

// ---------------------------------------------------------------------------
// Plain GEMM (non-cell outputs), 128x128 tile + LDS XOR swizzle.
// MODE 1: bf16 out remapped to feat layout. MODE 2: bf16 out to permuted
// Wdec rows. MODE 3: pose output (n<66, f32, [B,25,66]).
// ---------------------------------------------------------------------------
template <int MODE>
__launch_bounds__(256, 2)
__global__ void gemm_k(const unsigned short* __restrict__ A1, int lda1, int K,
                       const unsigned short* __restrict__ W, int ldw,
                       const float* __restrict__ bias,
                       float* __restrict__ outF,
                       unsigned short* __restrict__ outB, int ldout) {
  __shared__ __align__(16) unsigned short As[128 * 64];
  __shared__ __align__(16) unsigned short Bs[128 * 64];
  const int tid  = threadIdx.x;
  const int lane = tid & 63;
  const int wave = tid >> 6;
  const long m0  = (long)blockIdx.x * 128;
  const long n0  = (long)blockIdx.y * 128;
  const int wr   = (wave >> 1) * 64;
  const int wc   = (wave & 1) * 64;
  const int lrow = lane & 15;
  const int lk8  = (lane >> 4) * 8;

  f32x4 acc[4][4];
#pragma unroll
  for (int i = 0; i < 4; i++)
#pragma unroll
    for (int j = 0; j < 4; j++) acc[i][j] = f32x4{0.f, 0.f, 0.f, 0.f};

  for (int k0 = 0; k0 < K; k0 += 64) {
#pragma unroll
    for (int i = 0; i < 4; i++) {
      int c  = i * 256 + tid;
      int r  = c >> 3;
      int bs = ((c & 7) ^ (r & 7)) * 8;   // pre-swizzled global source block
      gload16(A1 + (m0 + r) * (long)lda1 + k0 + bs, &As[c * 8]);
      gload16(W + (n0 + r) * (long)ldw + k0 + bs, &Bs[c * 8]);
    }
    __syncthreads();
#pragma unroll
    for (int kk = 0; kk < 64; kk += 32) {
      const int g = (kk + lk8) >> 3;
      bf16x8 af[4], bw[4];
#pragma unroll
      for (int mi = 0; mi < 4; mi++) {
        int ra = wr + mi * 16 + lrow;
        af[mi] = *(const bf16x8*)&As[ra * 64 + ((g ^ (ra & 7)) << 3)];
      }
#pragma unroll
      for (int ni = 0; ni < 4; ni++) {
        int rbb = wc + ni * 16 + lrow;
        bw[ni] = *(const bf16x8*)&Bs[rbb * 64 + ((g ^ (rbb & 7)) << 3)];
      }
#pragma unroll
      for (int mi = 0; mi < 4; mi++)
#pragma unroll
        for (int ni = 0; ni < 4; ni++)
          acc[mi][ni] = __builtin_amdgcn_mfma_f32_16x16x32_bf16(
              af[mi], bw[ni], acc[mi][ni], 0, 0, 0);
    }
    __syncthreads();
  }

  const int rb = (lane >> 4) * 4;
  const int cb = lane & 15;
#pragma unroll
  for (int mi = 0; mi < 4; mi++) {
#pragma unroll
    for (int ni = 0; ni < 4; ni++) {
#pragma unroll
      for (int i = 0; i < 4; i++) {
        long m  = m0 + wr + mi * 16 + rb + i;
        long n  = n0 + wc + ni * 16 + cb;
        float v = acc[mi][ni][i];
        if constexpr (MODE == 1) {
          int xz = (int)(m / (B_ * TIN));
          int rr = (int)(m % (B_ * TIN));
          int b  = rr / TIN;
          int t  = rr % TIN;
          outB[(((long)(xz * TIN + t)) * B_ + b) * D_ + n] = f2bf(v + bias[n]);
        } else if constexpr (MODE == 2) {
          outB[(long)gate_pos((int)m) * ldout + n] = f2bf(v);
        } else {
          if (n < 66) {
            int t = (int)(m >> 10);
            int b = (int)(m & 1023);
            outF[(long)b * (TOUT * 66) + t * 66 + n] = v + bias[n];
          }
        }
      }
    }
  }
}

// ---------------------------------------------------------------------------
// Fused gates-GEMM + LSTM cell. BM=64 x BN=128 tile (2x grid vs round 10 ->
// 2 blocks/CU decoder, 4/CU encoder), 4 waves as 2(M)x2(N) of 32x64.
// W rows gate-interleaved; wave's 64 cols = 4 gates (ni) x 16 units (cb).
// LDS XOR swizzle on both A and B tiles. Epilogue computes c/h in-register.
// ---------------------------------------------------------------------------
__launch_bounds__(256, 2)
__global__ void gemm_cell_k(const unsigned short* __restrict__ A1,
                            const unsigned short* __restrict__ A2,
                            int lda1, int lda2, int K, int K1,
                            const unsigned short* __restrict__ W, int ldw,
                            const float* __restrict__ bias,
                            float* __restrict__ cst,
                            unsigned short* p0a, unsigned short* p0b,
                            unsigned short* p0c, unsigned short* p1a,
                            unsigned short* p1b, unsigned short* p1c,
                            long a1_zs, long a2_zs, long w_zs, long bias_zs) {
  __shared__ __align__(16) unsigned short As[64 * 64];    //  8KB
  __shared__ __align__(16) unsigned short Bs[128 * 64];   // 16KB
  const int tid  = threadIdx.x;
  const int lane = tid & 63;
  const int wave = tid >> 6;
  const int z    = blockIdx.z;
  const long m0  = (long)blockIdx.x * 64;
  const long n0  = (long)blockIdx.y * 128;
  const int wr   = (wave >> 1) * 32;
  const int wc   = (wave & 1) * 64;
  const int lrow = lane & 15;
  const int lk8  = (lane >> 4) * 8;

  f32x4 acc[2][4];
#pragma unroll
  for (int i = 0; i < 2; i++)
#pragma unroll
    for (int j = 0; j < 4; j++) acc[i][j] = f32x4{0.f, 0.f, 0.f, 0.f};

  const unsigned short* Wz  = W + (long)z * w_zs;
  const unsigned short* A1z = A1 + (long)z * a1_zs;
  const unsigned short* A2z = A2 + (long)z * a2_zs;

  for (int k0 = 0; k0 < K; k0 += 64) {
    const unsigned short* asrc;
    int ald, ak;
    if (k0 < K1) { asrc = A1z; ald = lda1; ak = k0; }
    else         { asrc = A2z; ald = lda2; ak = k0 - K1; }
#pragma unroll
    for (int i = 0; i < 2; i++) {           // A: 64 rows x 8 blocks
      int c  = i * 256 + tid;
      int r  = c >> 3;
      int bs = ((c & 7) ^ (r & 7)) * 8;
      gload16(asrc + (m0 + r) * (long)ald + ak + bs, &As[c * 8]);
    }
#pragma unroll
    for (int i = 0; i < 4; i++) {           // B: 128 rows x 8 blocks
      int c  = i * 256 + tid;
      int r  = c >> 3;
      int bs = ((c & 7) ^ (r & 7)) * 8;
      gload16(Wz + (n0 + r) * (long)ldw + k0 + bs, &Bs[c * 8]);
    }
    __syncthreads();
#pragma unroll
    for (int kk = 0; kk < 64; kk += 32) {
      const int g = (kk + lk8) >> 3;
      bf16x8 af[2], bw[4];
#pragma unroll
      for (int mi = 0; mi < 2; mi++) {
        int ra = wr + mi * 16 + lrow;
        af[mi] = *(const bf16x8*)&As[ra * 64 + ((g ^ (ra & 7)) << 3)];
      }
#pragma unroll
      for (int ni = 0; ni < 4; ni++) {
        int rbb = wc + ni * 16 + lrow;
        bw[ni] = *(const bf16x8*)&Bs[rbb * 64 + ((g ^ (rbb & 7)) << 3)];
      }
#pragma unroll
      for (int mi = 0; mi < 2; mi++)
#pragma unroll
        for (int ni = 0; ni < 4; ni++)
          acc[mi][ni] = __builtin_amdgcn_mfma_f32_16x16x32_bf16(
              af[mi], bw[ni], acc[mi][ni], 0, 0, 0);
    }
    __syncthreads();
  }

  // ---- fused cell epilogue -------------------------------------------------
  const int rb = (lane >> 4) * 4;
  const int cb = lane & 15;
  const int j  = (int)(n0 >> 2) + ((wave & 1) << 4) + cb;  // unit index
  const long bz = bias_zs * z + n0 + wc + cb;
  const float b0 = bias[bz];
  const float b1 = bias[bz + 16];
  const float b2 = bias[bz + 32];
  const float b3 = bias[bz + 48];
  unsigned short* pa = z ? p1a : p0a;
  unsigned short* pb = z ? p1b : p0b;
  unsigned short* pc = z ? p1c : p0c;
  float* cz = cst + (long)z * BH;
#pragma unroll
  for (int mi = 0; mi < 2; mi++) {
#pragma unroll
    for (int i = 0; i < 4; i++) {
      long m  = m0 + wr + mi * 16 + rb + i;
      float gi = acc[mi][0][i] + b0;
      float gf = acc[mi][1][i] + b1;
      float gg = acc[mi][2][i] + b2;
      float go = acc[mi][3][i] + b3;
      float si = 1.f / (1.f + __expf(-gi));
      float sf = 1.f / (1.f + __expf(-gf));
      float so = 1.f / (1.f + __expf(-go));
      float tg = 1.f - 2.f / (__expf(2.f * gg) + 1.f);
      long ci  = m * H_ + j;
      float cc = sf * cz[ci] + si * tg;
      cz[ci]   = cc;
      float tc = 1.f - 2.f / (__expf(2.f * cc) + 1.f);
      unsigned short hb = f2bf(so * tc);
      if (pa) pa[ci] = hb;
      if (pb) pb[ci] = hb;
      if (pc) pc[ci] = hb;
    }
  }
}

// ---------------------------------------------------------------------------
// Attention: block per batch row b. Vectorized ushort4 loads; 21 K/V tiles
// cached in registers (single cath pass). Slot 10 (h_n) is a separate ptr
// (double-buffered by decoder parity).
// ---------------------------------------------------------------------------
__launch_bounds__(256)
__global__ void attn_k(const unsigned short* __restrict__ cath,
                       const unsigned short* __restrict__ hn,
                       const float* __restrict__ c,
                       unsigned short* __restrict__ atth) {
  const int b   = blockIdx.x;
  const int tid = threadIdx.x;
  const int j4  = tid * 4;
  float4 cj = *(const float4*)(c + (long)b * H_ + j4);
  ushort4 kv[21];
  float ps[21];
#pragma unroll
  for (int s = 0; s < 21; s++) {
    const unsigned short* src =
        (s == 10) ? (hn + (long)b * H_) : (cath + ((long)s * B_ + b) * H_);
    ushort4 v = *(const ushort4*)(src + j4);
    kv[s] = v;
    ps[s] = bf2f(v.x) * cj.x + bf2f(v.y) * cj.y + bf2f(v.z) * cj.z +
            bf2f(v.w) * cj.w;
  }
#pragma unroll
  for (int s = 0; s < 21; s++) {
#pragma unroll
    for (int off = 32; off; off >>= 1) ps[s] += __shfl_down(ps[s], off);
  }
  __shared__ float sred[21][4];
  __shared__ float sw[21];
  const int wv = tid >> 6, ln = tid & 63;
  if (ln == 0) {
#pragma unroll
    for (int s = 0; s < 21; s++) sred[s][wv] = ps[s];
  }
  __syncthreads();
  if (tid < 21) sw[tid] = sred[tid][0] + sred[tid][1] + sred[tid][2] + sred[tid][3];
  __syncthreads();
  float mx = -1e30f;
#pragma unroll
  for (int s = 0; s < 21; s++) mx = fmaxf(mx, sw[s]);
  float wsum = 0.f;
  float w[21];
#pragma unroll
  for (int s = 0; s < 21; s++) { w[s] = __expf(sw[s] - mx); wsum += w[s]; }
  float inv = 1.f / wsum;
  float4 o = {0.f, 0.f, 0.f, 0.f};
#pragma unroll
  for (int s = 0; s < 21; s++) {
    o.x += w[s] * bf2f(kv[s].x);
    o.y += w[s] * bf2f(kv[s].y);
    o.z += w[s] * bf2f(kv[s].z);
    o.w += w[s] * bf2f(kv[s].w);
  }
  ushort4 ov;
  ov.x = f2bf(o.x * inv); ov.y = f2bf(o.y * inv);
  ov.z = f2bf(o.z * inv); ov.w = f2bf(o.w * inv);
  *(ushort4*)(atth + (long)b * H_ + j4) = ov;
}

// ---------------------------------------------------------------------------
// Prep (vec8): each thread handles 8 contiguous elements. Weight rows are
// written at gate-interleaved positions (gate_orig).
// ---------------------------------------------------------------------------
__global__ void prep_k(const float* __restrict__ x, const float* __restrict__ zin,
                       const float* __restrict__ wf,
                       const float* __restrict__ enc_wih, const float* __restrict__ enc_whh,
                       const float* __restrict__ encp_wih, const float* __restrict__ encp_whh,
                       const float* __restrict__ dec_whh, const float* __restrict__ dec_wih,
                       const float* __restrict__ lin_w, const float* __restrict__ pose_w,
                       const float* __restrict__ enc_bih, const float* __restrict__ enc_bhh,
                       const float* __restrict__ encp_bih, const float* __restrict__ encp_bhh,
                       unsigned short* WcatE, unsigned short* Wdec,
                       unsigned short* dwih_bf, unsigned short* lin_wT,
                       unsigned short* pose_pad, unsigned short* wf_pad,
                       unsigned short* x_pad, unsigned short* h_e,
                       float* c_enc, float* bias_e) {
  long v = (long)blockIdx.x * 256 + threadIdx.x;
  if (v < 786432) {  // WcatE z0 = [enc_whh | enc_wih], permuted rows
    int n = (int)(v / 192), k8 = (int)(v % 192) * 8;
    int ro = gate_orig(n);
    const float* s = (k8 < 1024) ? enc_whh + (long)ro * 1024 + k8
                                 : enc_wih + (long)ro * 512 + (k8 - 1024);
    cvt8(s, WcatE + (long)n * 1536 + k8);
    return;
  }
  v -= 786432;
  if (v < 786432) {  // WcatE z1
    int n = (int)(v / 192), k8 = (int)(v % 192) * 8;
    int ro = gate_orig(n);
    const float* s = (k8 < 1024) ? encp_whh + (long)ro * 1024 + k8
                                 : encp_wih + (long)ro * 512 + (k8 - 1024);
    cvt8(s, WcatE + 6291456L + (long)n * 1536 + k8);
    return;
  }
  v -= 786432;
  if (v < 524288) {  // Wdec cols 0..1023 = dec_whh, permuted rows
    int n = (int)(v / 128), k8 = (int)(v % 128) * 8;
    cvt8(dec_whh + (long)gate_orig(n) * 1024 + k8, Wdec + (long)n * 2048 + k8);
    return;
  }
  v -= 524288;
  if (v < 262144) {  // dwih copy (GEMM A operand, original row order)
    long e = v * 8;
    cvt8(dec_wih + e, dwih_bf + e);
    return;
  }
  v -= 262144;
  if (v < 65536) {  // lin_wT[h][d] = lin_w[d][h]
    int h = (int)(v / 64), d8 = (int)(v % 64) * 8;
    ushort8v o;
#pragma unroll
    for (int q = 0; q < 8; q++) o[q] = f2bf(lin_w[(long)(d8 + q) * 1024 + h]);
    *(ushort8v*)(lin_wT + (long)h * 512 + d8) = o;
    return;
  }
  v -= 65536;
  if (v < 16384) {  // pose_w padded to 128 rows
    int r = (int)(v / 128), c8 = (int)(v % 128) * 8;
    if (r < 66) {
      cvt8(pose_w + (long)r * 1024 + c8, pose_pad + (long)r * 1024 + c8);
    } else {
      ushort8v o;
#pragma unroll
      for (int q = 0; q < 8; q++) o[q] = 0;
      *(ushort8v*)(pose_pad + (long)r * 1024 + c8) = o;
    }
    return;
  }
  v -= 16384;
  if (v < 8192) {  // wf padded to 128 cols
    int r = (int)(v / 16), c8 = (int)(v % 16) * 8;
    ushort8v o;
#pragma unroll
    for (int q = 0; q < 8; q++) {
      int cc = c8 + q;
      o[q] = (cc < 66) ? f2bf(wf[(long)r * 66 + cc]) : 0;
    }
    *(ushort8v*)(wf_pad + (long)r * 128 + c8) = o;
    return;
  }
  v -= 8192;
  if (v < 327680) {  // x/z padded: row r = xz*10240 + b*10 + t
    int r = (int)(v / 16), c8 = (int)(v % 16) * 8;
    ushort8v o;
#pragma unroll
    for (int q = 0; q < 8; q++) {
      int cc = c8 + q;
      float val = 0.f;
      if (cc < 66)
        val = (r < 10240) ? x[(long)r * 66 + cc] : zin[(long)(r - 10240) * 66 + cc];
      o[q] = f2bf(val);
    }
    *(ushort8v*)(x_pad + (long)r * 128 + c8) = o;
    return;
  }
  v -= 327680;
  if (v < 262144) {  // h_e parity-0 zeros (2 z slots)
    ushort8v o;
#pragma unroll
    for (int q = 0; q < 8; q++) o[q] = 0;
    *(ushort8v*)(h_e + v * 8) = o;
    return;
  }
  v -= 262144;
  if (v < 262144) {  // c_enc zeros
    float4 z4 = {0.f, 0.f, 0.f, 0.f};
    ((float4*)(c_enc + v * 8))[0] = z4;
    ((float4*)(c_enc + v * 8))[1] = z4;
    return;
  }
  v -= 262144;
  if (v < 1024) {  // bias_e permuted
    long e = v * 8;
#pragma unroll
    for (int q = 0; q < 8; q++) {
      long idx = e + q;
      int zz = (int)(idx >> 12);
      int ro = gate_orig((int)(idx & 4095));
      bias_e[idx] = zz ? (encp_bih[ro] + encp_bhh[ro])
                       : (enc_bih[ro] + enc_bhh[ro]);
    }
    return;
  }
}

// bias_dec[pos(r)] = dec_bih[r] + dec_bhh[r] + dec_wih[r,:] @ lin_b
__global__ void biasd_k(const float* __restrict__ dec_wih,
                        const float* __restrict__ lin_b,
                        const float* __restrict__ dec_bih,
                        const float* __restrict__ dec_bhh,
                        float* __restrict__ bias_d) {
  const int r  = blockIdx.x;
  const int ln = threadIdx.x;  // 64
  const float* row = dec_wih + (long)r * 512;
  float a = 0.f;
  for (int k = ln; k < 512; k += 64) a += row[k] * lin_b[k];
#pragma unroll
  for (int off = 32; off; off >>= 1) a += __shfl_down(a, off);
  if (ln == 0) bias_d[gate_pos(r)] = a + dec_bih[r] + dec_bhh[r];
}

// ws_size-insufficient sentinel: fill d_out with (float)ws_size for diagnosis.
__global__ void sentinel_k(float* out, long n, float v) {
  long i = (long)blockIdx.x * 256 + threadIdx.x;
  if (i < n) out[i] = v;
}

// ---------------------------------------------------------------------------
extern "C" void kernel_launch(void* const* d_in, const int* in_sizes, int n_in,
                              void* d_out, int out_size, void* d_ws,
                              size_t ws_size, hipStream_t stream) {
  const float* x        = (const float*)d_in[0];
  const float* zin      = (const float*)d_in[1];
  const float* wf       = (const float*)d_in[2];
  const float* bf       = (const float*)d_in[3];
  const float* enc_wih  = (const float*)d_in[4];
  const float* enc_whh  = (const float*)d_in[5];
  const float* enc_bih  = (const float*)d_in[6];
  const float* enc_bhh  = (const float*)d_in[7];
  const float* encp_wih = (const float*)d_in[8];
  const float* encp_whh = (const float*)d_in[9];
  const float* encp_bih = (const float*)d_in[10];
  const float* encp_bhh = (const float*)d_in[11];
  const float* dec_wih  = (const float*)d_in[12];
  const float* dec_whh  = (const float*)d_in[13];
  const float* dec_bih  = (const float*)d_in[14];
  const float* dec_bhh  = (const float*)d_in[15];
  const float* lin_w    = (const float*)d_in[16];
  const float* lin_b    = (const float*)d_in[17];
  const float* pose_w   = (const float*)d_in[18];
  const float* pose_b   = (const float*)d_in[19];

  char* ws = (char*)d_ws;
  size_t off = 0;
  auto alloc = [&](size_t bytes) {
    void* p = ws + off;
    off += (bytes + 255) & ~(size_t)255;
    return p;
  };
  // --- region A (dead after encoder; hs aliases its start in decoder) ------
  size_t regionA_start = off;
  unsigned short* WcatE = (unsigned short*)alloc(2L * 4096 * 1536 * 2);  // 25.2MB
  unsigned short* dwih  = (unsigned short*)alloc(4096L * 512 * 2);       //  4.2MB
  unsigned short* linT  = (unsigned short*)alloc(1024L * 512 * 2);       //  1.0MB
  unsigned short* xpad  = (unsigned short*)alloc(20480L * 128 * 2);      //  5.2MB
  unsigned short* feat  = (unsigned short*)alloc(20L * B_ * D_ * 2);     // 21.0MB
  unsigned short* h_e   = (unsigned short*)alloc(4L * BH * 2);  // [par][z] 8.4MB
  unsigned short* hs    = (unsigned short*)(ws + regionA_start);         // 52.4MB alias
  // --- persistent region ---------------------------------------------------
  unsigned short* Wdec  = (unsigned short*)alloc(4096L * 2048 * 2);      // 16.8MB
  unsigned short* posep = (unsigned short*)alloc(128L * 1024 * 2);
  unsigned short* wfp   = (unsigned short*)alloc(512L * 128 * 2);
  unsigned short* cath  = (unsigned short*)alloc(21L * BH * 2);          // 44.0MB
  unsigned short* hd    = (unsigned short*)alloc(2L * BH * 2);  // [par]   4.2MB
  float*          cenc  = (float*)alloc(2L * BH * 4);                    //  8.4MB
  unsigned short* atth  = (unsigned short*)alloc((long)BH * 2);
  float*          biasE = (float*)alloc(2L * G_ * 4);
  float*          biasD = (float*)alloc((long)G_ * 4);

  if (off > ws_size) {
    sentinel_k<<<(out_size + 255) / 256, 256, 0, stream>>>(
        (float*)d_out, out_size, (float)ws_size);
    return;
  }

  prep_k<<<12900, 256, 0, stream>>>(x, zin, wf, enc_wih, enc_whh, encp_wih,
                                    encp_whh, dec_whh, dec_wih, lin_w, pose_w,
                                    enc_bih, enc_bhh, encp_bih, encp_bhh,
                                    WcatE, Wdec, dwih, linT, posep, wfp, xpad,
                                    h_e, cenc, biasE);
  biasd_k<<<4096, 64, 0, stream>>>(dec_wih, lin_b, dec_bih, dec_bhh, biasD);

  // W2 = dec_wih @ lin_w -> Wdec cols 1024..2047 (permuted rows)
  gemm_k<2><<<dim3(32, 8, 1), 256, 0, stream>>>(
      dwih, 512, 512, linT, 512, nullptr, nullptr, Wdec + 1024, 2048);

  // feat = [x;z]_pad @ wf_pad.T + bf
  gemm_k<1><<<dim3(160, 4, 1), 256, 0, stream>>>(
      xpad, 128, 128, wfp, 128, bf, nullptr, feat, 512);

  // encoders (z=0: enc, z=1: enc_post), fused GEMM+cell, h double-buffered
  for (int t = 0; t < TIN; t++) {
    unsigned short* hr = h_e + (long)(t & 1) * 2 * BH;        // read parity
    unsigned short* hw = h_e + (long)((t + 1) & 1) * 2 * BH;  // write parity
    gemm_cell_k<<<dim3(16, 32, 2), 256, 0, stream>>>(
        hr, feat + (long)t * B_ * D_, 1024, 512, 1536, 1024, WcatE, 1536,
        biasE, cenc,
        /*z0*/ hw, cath + (long)t * BH, (t == TIN - 1) ? hd : nullptr,
        /*z1*/ hw + BH, cath + (long)(11 + t) * BH, nullptr,
        (long)BH, (long)TIN * B_ * D_, 4096L * 1536, (long)G_);
  }

  // decoder: h_n double-buffered in hd[par]; c state continues in cenc[z=0]
  for (int d = 0; d < TOUT; d++) {
    unsigned short* hr = hd + (long)(d & 1) * BH;
    unsigned short* hw = hd + (long)((d + 1) & 1) * BH;
    attn_k<<<1024, 256, 0, stream>>>(cath, hr, cenc, atth);
    gemm_cell_k<<<dim3(16, 32, 1), 256, 0, stream>>>(
        atth, hr, 1024, 1024, 2048, 1024, Wdec, 2048, biasD, cenc,
        hw, hs + (long)d * BH, nullptr, nullptr, nullptr, nullptr,
        0, 0, 0, 0);
  }

  // out[b,t,p] = hs[t,b,:] @ pose_w.T + pose_b
  gemm_k<3><<<dim3(200, 1, 1), 256, 0, stream>>>(
      hs, 1024, 1024, posep, 1024, pose_b, (float*)d_out, nullptr, 0);
}